// Round 6
// baseline (201963.538 us; speedup 1.0000x reference)
//
#include <hip/hip_runtime.h>
#include <math.h>

#define T_STEPS 16384
#define IN 512
#define HID 1024
#define NC 512
#define NWG 256
#define TPB 256
#define TB 32           // t-rows per block in dense kernel
typedef unsigned long long ull;

__device__ __forceinline__ float sigmoidf_(float x) { return 1.f / (1.f + expf(-x)); }

// DPP-based wave sum; ctrl must be a compile-time constant.
template <int CTRL>
__device__ __forceinline__ float dpp_add_(float x) {
    int y = __builtin_amdgcn_update_dpp(0, __float_as_int(x), CTRL, 0xf, 0xf, true);
    return x + __int_as_float(y);
}
// After this, lane 63 holds the sum of all 64 lanes.
__device__ __forceinline__ float wave_sum_l63(float x) {
    x = dpp_add_<0x111>(x);  // row_shr:1
    x = dpp_add_<0x112>(x);  // row_shr:2
    x = dpp_add_<0x114>(x);  // row_shr:4
    x = dpp_add_<0x118>(x);  // row_shr:8  -> lane15 of each row = row sum
    x = dpp_add_<0x142>(x);  // row_bcast15: l31=sum(0..31), l63=sum(32..63)
    x = dpp_add_<0x143>(x);  // row_bcast31: l63=total
    return x;
}

// ---------------- Kernel 0: seed epoch-tagged h buffer ----------------
// bufp[p][j] = {epoch:u32 | h:f32}. h_t carries epoch t+2, parity (t+1)&1;
// h0 -> epoch 1, parity 0. ws is NOT re-poisoned between replays -> reset both.
__global__ void init_k(const float* __restrict__ h0, ull* __restrict__ bufp)
{
    const int j = threadIdx.x;  // 1024 threads, 1 block
    bufp[j]       = (1ull << 32) | (ull)__float_as_uint(h0[j]);
    bufp[HID + j] = 0ull;
}

// ---------------- Kernel 1: persistent LSTM recurrence ----------------
// 256 WGs x 256 threads (4 waves), 1 WG/CU. Wave wv owns h elem j=wg*4+wv and
// its 4 gate rows. NO LDS, NO barriers: each wave polls exactly the 16
// epoch-tagged words its FMAs need (poll IS the gather), with cached loads +
// explicit acquire-fence (buffer_inv) refresh so XCD-mates share L2 lines.
__global__ __launch_bounds__(TPB, 1) void lstm_rec(
    const float* __restrict__ X,     // [T, IN]
    const float* __restrict__ c0,    // [HID]
    const float* __restrict__ W_ih,  // [4H, IN]
    const float* __restrict__ W_hh,  // [4H, HID]
    const float* __restrict__ b_ih,  // [4H]
    const float* __restrict__ b_hh,  // [4H]
    float* __restrict__ h_all,       // ws [T, HID]
    ull* __restrict__ bufp)          // ws [2][HID] epoch|h
{
    const int tid  = threadIdx.x;
    const int wg   = blockIdx.x;
    const int lane = tid & 63;
    const int wv   = tid >> 6;
    const int j    = wg * 4 + wv;    // owned h element
    const int kb   = lane * 4;

    // weights for the 4 gate rows of elem j: lane covers k = kb + c*256, c=0..5
    float4 w[4][6];
    float bias[4];
    #pragma unroll
    for (int q = 0; q < 4; ++q) {
        const int row = q * HID + j;
        #pragma unroll
        for (int c = 0; c < 6; ++c) {
            const int k = kb + c * 256;
            w[q][c] = (k < IN)
                ? *(const float4*)&W_ih[(size_t)row * IN + k]
                : *(const float4*)&W_hh[(size_t)row * HID + (k - IN)];
        }
        bias[q] = b_ih[row] + b_hh[row];
    }
    float c_state = c0[j];   // only lane 63's copy is live
    bool dead = false;

    for (int t = 0; t < T_STEPS; ++t) {
        const int p = t & 1;
        const unsigned want = (unsigned)(t + 1);

        // x slice to registers (issued before the poll: latency overlap)
        const float* xr = X + (size_t)t * IN;
        const float4 x0 = *(const float4*)&xr[kb];
        const float4 x1 = *(const float4*)&xr[kb + 256];

        // ---- poll the 16 h words this lane consumes, straight to registers ----
        ull* src = bufp + (size_t)p * HID;
        ull v[16];
        #pragma unroll
        for (int c = 0; c < 4; ++c) {
            #pragma unroll
            for (int i = 0; i < 4; ++i)
                v[c * 4 + i] = __hip_atomic_load(&src[kb + c * 256 + i],
                                                 __ATOMIC_RELAXED, __HIP_MEMORY_SCOPE_WORKGROUP);
        }
        unsigned spn = 0;
        for (;;) {
            bool st[4];
            bool any = false;
            #pragma unroll
            for (int c = 0; c < 4; ++c) {
                const unsigned em = min(min((unsigned)(v[c*4+0] >> 32), (unsigned)(v[c*4+1] >> 32)),
                                        min((unsigned)(v[c*4+2] >> 32), (unsigned)(v[c*4+3] >> 32)));
                st[c] = (em < want);
                any |= st[c];
            }
            if (!__any((int)any) || dead) break;
            __builtin_amdgcn_fence(__ATOMIC_ACQUIRE, "agent");   // waitcnt + inv L1/L2
            #pragma unroll
            for (int c = 0; c < 4; ++c) {
                if (st[c]) {
                    #pragma unroll
                    for (int i = 0; i < 4; ++i)
                        v[c * 4 + i] = __hip_atomic_load(&src[kb + c * 256 + i],
                                                         __ATOMIC_RELAXED, __HIP_MEMORY_SCOPE_WORKGROUP);
                }
            }
            if (++spn > 150000u) dead = true;   // fail, don't hang
        }

        // ---- GEMV: 4 gate rows, weights + h all in registers ----
        float acc[4];
        #pragma unroll
        for (int q = 0; q < 4; ++q) {
            acc[q] = w[q][0].x*x0.x + w[q][0].y*x0.y + w[q][0].z*x0.z + w[q][0].w*x0.w
                   + w[q][1].x*x1.x + w[q][1].y*x1.y + w[q][1].z*x1.z + w[q][1].w*x1.w;
        }
        #pragma unroll
        for (int c = 0; c < 4; ++c) {
            const float h0v = __uint_as_float((unsigned)v[c*4+0]);
            const float h1v = __uint_as_float((unsigned)v[c*4+1]);
            const float h2v = __uint_as_float((unsigned)v[c*4+2]);
            const float h3v = __uint_as_float((unsigned)v[c*4+3]);
            #pragma unroll
            for (int q = 0; q < 4; ++q) {
                const float4 wc = w[q][2 + c];
                acc[q] += wc.x * h0v + wc.y * h1v + wc.z * h2v + wc.w * h3v;
            }
        }

        // DPP reduce: lane 63 gets each gate's full dot product
        float g0 = wave_sum_l63(acc[0]);
        float g1 = wave_sum_l63(acc[1]);
        float g2 = wave_sum_l63(acc[2]);
        float g3 = wave_sum_l63(acc[3]);

        if (lane == 63) {
            const float iv = sigmoidf_(g0 + bias[0]);
            const float fv = sigmoidf_(g1 + bias[1]);
            const float gv = tanhf   (g2 + bias[2]);
            const float ov = sigmoidf_(g3 + bias[3]);
            c_state = fv * c_state + iv * gv;
            const float h = ov * tanhf(c_state);
            // publish FIRST (critical path), h_all after
            __hip_atomic_store(&bufp[(size_t)(p ^ 1) * HID + j],
                ((ull)(unsigned)(t + 2) << 32) | (ull)__float_as_uint(h),
                __ATOMIC_RELAXED, __HIP_MEMORY_SCOPE_AGENT);
            h_all[(size_t)t * HID + j] = h;
        }
    }
}

// ---------------- Kernel 2: out_t = softmax_C(h_t @ Wd^T + bd) ----------------
__global__ __launch_bounds__(256, 2) void dense_softmax(
    const float* __restrict__ h_all, const float* __restrict__ Wd,
    const float* __restrict__ bd, float* __restrict__ P)
{
    __shared__ float buf[TB * NC];    // 64KB union: hs[TB][128] then ls[TB][NC]
    const int tid = threadIdx.x;
    const int t0  = blockIdx.x * TB;
    const int c0 = tid, c1 = tid + 256;

    float acc0[TB], acc1[TB];
    #pragma unroll
    for (int r = 0; r < TB; ++r) { acc0[r] = 0.f; acc1[r] = 0.f; }

    const float4* wrow0 = (const float4*)&Wd[(size_t)c0 * HID];
    const float4* wrow1 = (const float4*)&Wd[(size_t)c1 * HID];

    for (int kc = 0; kc < HID / 128; ++kc) {
        #pragma unroll
        for (int i = 0; i < 4; ++i) {
            const int idx4 = tid + i * 256;
            const int r = idx4 >> 5, kk = (idx4 & 31) * 4;
            *(float4*)&buf[r * 128 + kk] =
                *(const float4*)&h_all[(size_t)(t0 + r) * HID + kc * 128 + kk];
        }
        __syncthreads();
        #pragma unroll 8
        for (int k4 = 0; k4 < 32; ++k4) {
            const float4 a = wrow0[kc * 32 + k4];
            const float4 b = wrow1[kc * 32 + k4];
            #pragma unroll
            for (int r = 0; r < TB; ++r) {
                const float4 h4 = *(const float4*)&buf[r * 128 + k4 * 4];
                acc0[r] += a.x*h4.x + a.y*h4.y + a.z*h4.z + a.w*h4.w;
                acc1[r] += b.x*h4.x + b.y*h4.y + b.z*h4.z + b.w*h4.w;
            }
        }
        __syncthreads();
    }

    const float bb0 = bd[c0], bb1 = bd[c1];
    #pragma unroll
    for (int r = 0; r < TB; ++r) {
        buf[r * NC + c0] = acc0[r] + bb0;
        buf[r * NC + c1] = acc1[r] + bb1;
    }
    __syncthreads();

    const int lane = tid & 63, wvv = tid >> 6;
    for (int rr = 0; rr < 8; ++rr) {
        const int r = wvv * 8 + rr;
        float vals[8];
        float m = -1e30f;
        #pragma unroll
        for (int jx = 0; jx < 8; ++jx) { vals[jx] = buf[r * NC + lane + 64 * jx]; m = fmaxf(m, vals[jx]); }
        #pragma unroll
        for (int off = 32; off; off >>= 1) m = fmaxf(m, __shfl_xor(m, off));
        float s = 0.f;
        #pragma unroll
        for (int jx = 0; jx < 8; ++jx) { vals[jx] = expf(vals[jx] - m); s += vals[jx]; }
        #pragma unroll
        for (int off = 32; off; off >>= 1) s += __shfl_xor(s, off);
        const float inv = 1.f / s;
        #pragma unroll
        for (int jx = 0; jx < 8; ++jx)
            P[(size_t)(t0 + r) * NC + lane + 64 * jx] = vals[jx] * inv;
    }
}

// ---------------- Kernel 3a: colsum[c] = sum_t exp(P[t][c]) ----------------
__global__ __launch_bounds__(256) void colsum_k(const float* __restrict__ P, float* __restrict__ cs)
{
    const int tid = threadIdx.x;
    const int c  = blockIdx.x * 16 + (tid & 15);
    const int tr = tid >> 4;
    float s = 0.f;
    #pragma unroll 8
    for (int t = tr; t < T_STEPS; t += 16) s += expf(P[(size_t)t * NC + c]);
    __shared__ float red[256];
    red[tid] = s; __syncthreads();
    for (int off = 128; off >= 16; off >>= 1) {
        if (tid < off) red[tid] += red[tid + off];
        __syncthreads();
    }
    if (tid < 16) cs[blockIdx.x * 16 + tid] = red[tid];
}

// ---------------- Kernel 3b: out = exp(P) / colsum ----------------
__global__ __launch_bounds__(256) void norm_k(float* P, const float* __restrict__ cs)
{
    size_t i = (size_t)blockIdx.x * 256 + threadIdx.x;
    const size_t n = (size_t)T_STEPS * NC;
    const size_t stride = (size_t)gridDim.x * 256;
    for (; i < n; i += stride) P[i] = expf(P[i]) / cs[i & (NC - 1)];
}

extern "C" void kernel_launch(void* const* d_in, const int* in_sizes, int n_in,
                              void* d_out, int out_size, void* d_ws, size_t ws_size,
                              hipStream_t stream) {
    const float* X    = (const float*)d_in[0];
    const float* h0   = (const float*)d_in[1];
    const float* c0   = (const float*)d_in[2];
    const float* W_ih = (const float*)d_in[3];
    const float* W_hh = (const float*)d_in[4];
    const float* b_ih = (const float*)d_in[5];
    const float* b_hh = (const float*)d_in[6];
    const float* Wd   = (const float*)d_in[7];
    const float* bd   = (const float*)d_in[8];
    float* out = (float*)d_out;

    char* ws = (char*)d_ws;
    ull*   bufp  = (ull*)ws;                     // [2][HID] epoch|h
    float* cs    = (float*)(ws + 16384);         // [NC]
    float* h_all = (float*)(ws + 32768);         // [T, HID]

    init_k<<<1, HID, 0, stream>>>(h0, bufp);
    lstm_rec<<<NWG, TPB, 0, stream>>>(X, c0, W_ih, W_hh, b_ih, b_hh, h_all, bufp);
    dense_softmax<<<T_STEPS / TB, 256, 0, stream>>>(h_all, Wd, bd, out);
    colsum_k<<<NC / 16, 256, 0, stream>>>(out, cs);
    norm_k<<<2048, 256, 0, stream>>>(out, cs);
}

// Round 7
// 85358.521 us; speedup vs baseline: 2.3661x; 2.3661x over previous
//
#include <hip/hip_runtime.h>
#include <math.h>

#define T_STEPS 16384
#define IN 512
#define HID 1024
#define NC 512
#define NWG 64
#define TPB 512
#define TB 32           // t-rows per block in dense kernel
typedef unsigned long long ull;

__device__ __forceinline__ float sigmoidf_(float x) { return 1.f / (1.f + expf(-x)); }

// ---------------- Kernel 0: seed epoch-tagged h buffer ----------------
// bufp[p][j] = {epoch:u32 | h:f32}. h_t carries epoch t+2, parity (t+1)&1;
// h0 -> epoch 1, parity 0. ws is NOT re-poisoned between replays -> reset both.
__global__ void init_k(const float* __restrict__ h0, ull* __restrict__ bufp)
{
    const int j = threadIdx.x;  // 1024 threads, 1 block
    bufp[j]       = (1ull << 32) | (ull)__float_as_uint(h0[j]);
    bufp[HID + j] = 0ull;
}

// ---------------- Kernel 1: persistent LSTM recurrence ----------------
// 64 WGs x 512 threads (8 waves). WG wg owns h elems [wg*16, wg*16+16);
// wave wv owns elems je0=wg*16+wv*2 +{0,1} and their 8 gate rows (4 gates x 2).
// Weights in VGPRs (192 floats/lane). Poll: thread stages fused words
// {tid*2, tid*2+1} into LDS; stale-selective reload; __syncthreads_and detect.
// 64 participants -> 512 KB/sweep MALL traffic (4x less than 256 WGs).
__global__ __launch_bounds__(TPB, 2) void lstm_rec(
    const float* __restrict__ X,     // [T, IN]
    const float* __restrict__ c0,    // [HID]
    const float* __restrict__ W_ih,  // [4H, IN]
    const float* __restrict__ W_hh,  // [4H, HID]
    const float* __restrict__ b_ih,  // [4H]
    const float* __restrict__ b_hh,  // [4H]
    float* __restrict__ h_all,       // ws [T, HID]
    ull* __restrict__ bufp)          // ws [2][HID] epoch|h
{
    __shared__ float svh[HID];

    const int tid  = threadIdx.x;
    const int wg   = blockIdx.x;
    const int lane = tid & 63;
    const int wv   = tid >> 6;          // 0..7
    const int je0  = wg * 16 + wv * 2;  // wave's first h element
    const int kb   = lane * 4;

    // --- weights for 8 rows (r = q*2+e): row = q*HID + je0+e ---
    float4 w[8][6];
    float bias[8];
    #pragma unroll
    for (int q = 0; q < 4; ++q) {
        #pragma unroll
        for (int e = 0; e < 2; ++e) {
            const int r = q * 2 + e;
            const int row = q * HID + je0 + e;
            #pragma unroll
            for (int c = 0; c < 6; ++c) {
                const int k = kb + c * 256;
                w[r][c] = (k < IN)
                    ? *(const float4*)&W_ih[(size_t)row * IN + k]
                    : *(const float4*)&W_hh[(size_t)row * HID + (k - IN)];
            }
            bias[r] = b_ih[row] + b_hh[row];
        }
    }
    // lane 0 tracks elem je0, lanes>=1 track elem je0+1 (only lanes 0,1 store)
    const int esel = (lane == 0) ? 0 : 1;
    float c_state = c0[je0 + esel];
    bool dead = false;
    __syncthreads();

    for (int t = 0; t < T_STEPS; ++t) {
        const int p = t & 1;
        const unsigned want = (unsigned)(t + 1);

        // x slice to registers (issued before the poll: latency overlap)
        const float* xr = X + (size_t)t * IN;
        const float4 x0 = *(const float4*)&xr[kb];
        const float4 x1 = *(const float4*)&xr[kb + 256];

        // ---- poll: thread owns fused words tid*2, tid*2+1 (16B coalesced) ----
        ull* src = bufp + (size_t)p * HID;
        const int i0 = tid * 2;
        ull v0 = __hip_atomic_load(&src[i0],     __ATOMIC_RELAXED, __HIP_MEMORY_SCOPE_AGENT);
        ull v1 = __hip_atomic_load(&src[i0 + 1], __ATOMIC_RELAXED, __HIP_MEMORY_SCOPE_AGENT);
        unsigned spn = 0;
        int ok;
        do {
            if ((unsigned)(v0 >> 32) < want)
                v0 = __hip_atomic_load(&src[i0],     __ATOMIC_RELAXED, __HIP_MEMORY_SCOPE_AGENT);
            if ((unsigned)(v1 >> 32) < want)
                v1 = __hip_atomic_load(&src[i0 + 1], __ATOMIC_RELAXED, __HIP_MEMORY_SCOPE_AGENT);
            const bool fresh = ((unsigned)(v0 >> 32) >= want) & ((unsigned)(v1 >> 32) >= want);
            svh[i0]     = __uint_as_float((unsigned)v0);
            svh[i0 + 1] = __uint_as_float((unsigned)v1);
            const int timeout = (++spn > 2000000u);   // fail, don't hang
            ok = __syncthreads_and((int)fresh | timeout | (int)dead);
        } while (!ok);
        if (spn > 2000000u) dead = true;

        // ---- read h slice from LDS, then release svh for next step ----
        const float4 s0 = *(const float4*)&svh[kb];
        const float4 s1 = *(const float4*)&svh[kb + 256];
        const float4 s2 = *(const float4*)&svh[kb + 512];
        const float4 s3 = *(const float4*)&svh[kb + 768];
        __syncthreads();

        // ---- GEMV: 8 rows x 24 elems/lane, weights in regs ----
        float acc[8];
        #pragma unroll
        for (int r = 0; r < 8; ++r) {
            acc[r] = w[r][0].x*x0.x + w[r][0].y*x0.y + w[r][0].z*x0.z + w[r][0].w*x0.w
                   + w[r][1].x*x1.x + w[r][1].y*x1.y + w[r][1].z*x1.z + w[r][1].w*x1.w
                   + w[r][2].x*s0.x + w[r][2].y*s0.y + w[r][2].z*s0.z + w[r][2].w*s0.w
                   + w[r][3].x*s1.x + w[r][3].y*s1.y + w[r][3].z*s1.z + w[r][3].w*s1.w
                   + w[r][4].x*s2.x + w[r][4].y*s2.y + w[r][4].z*s2.z + w[r][4].w*s2.w
                   + w[r][5].x*s3.x + w[r][5].y*s3.y + w[r][5].z*s3.z + w[r][5].w*s3.w;
        }
        // full butterfly: every lane ends with all 8 row sums
        #pragma unroll
        for (int r = 0; r < 8; ++r) {
            float s = acc[r];
            #pragma unroll
            for (int off = 32; off; off >>= 1) s += __shfl_xor(s, off);
            acc[r] = s;
        }

        // constant-index selects (no runtime array indexing -> no scratch)
        const float gi = (esel == 0) ? acc[0] + bias[0] : acc[1] + bias[1];
        const float gf = (esel == 0) ? acc[2] + bias[2] : acc[3] + bias[3];
        const float gg = (esel == 0) ? acc[4] + bias[4] : acc[5] + bias[5];
        const float go = (esel == 0) ? acc[6] + bias[6] : acc[7] + bias[7];
        const float iv = sigmoidf_(gi);
        const float fv = sigmoidf_(gf);
        const float gv = tanhf(gg);
        const float ov = sigmoidf_(go);
        c_state = fv * c_state + iv * gv;
        const float h = ov * tanhf(c_state);

        if (lane < 2) {
            const int j = je0 + lane;
            // publish FIRST (critical path), h_all after
            __hip_atomic_store(&bufp[(size_t)(p ^ 1) * HID + j],
                ((ull)(unsigned)(t + 2) << 32) | (ull)__float_as_uint(h),
                __ATOMIC_RELAXED, __HIP_MEMORY_SCOPE_AGENT);
            h_all[(size_t)t * HID + j] = h;
        }
    }
}

// ---------------- Kernel 2: out_t = softmax_C(h_t @ Wd^T + bd) ----------------
__global__ __launch_bounds__(256, 2) void dense_softmax(
    const float* __restrict__ h_all, const float* __restrict__ Wd,
    const float* __restrict__ bd, float* __restrict__ P)
{
    __shared__ float buf[TB * NC];    // 64KB union: hs[TB][128] then ls[TB][NC]
    const int tid = threadIdx.x;
    const int t0  = blockIdx.x * TB;
    const int c0 = tid, c1 = tid + 256;

    float acc0[TB], acc1[TB];
    #pragma unroll
    for (int r = 0; r < TB; ++r) { acc0[r] = 0.f; acc1[r] = 0.f; }

    const float4* wrow0 = (const float4*)&Wd[(size_t)c0 * HID];
    const float4* wrow1 = (const float4*)&Wd[(size_t)c1 * HID];

    for (int kc = 0; kc < HID / 128; ++kc) {
        #pragma unroll
        for (int i = 0; i < 4; ++i) {
            const int idx4 = tid + i * 256;
            const int r = idx4 >> 5, kk = (idx4 & 31) * 4;
            *(float4*)&buf[r * 128 + kk] =
                *(const float4*)&h_all[(size_t)(t0 + r) * HID + kc * 128 + kk];
        }
        __syncthreads();
        #pragma unroll 8
        for (int k4 = 0; k4 < 32; ++k4) {
            const float4 a = wrow0[kc * 32 + k4];
            const float4 b = wrow1[kc * 32 + k4];
            #pragma unroll
            for (int r = 0; r < TB; ++r) {
                const float4 h4 = *(const float4*)&buf[r * 128 + k4 * 4];
                acc0[r] += a.x*h4.x + a.y*h4.y + a.z*h4.z + a.w*h4.w;
                acc1[r] += b.x*h4.x + b.y*h4.y + b.z*h4.z + b.w*h4.w;
            }
        }
        __syncthreads();
    }

    const float bb0 = bd[c0], bb1 = bd[c1];
    #pragma unroll
    for (int r = 0; r < TB; ++r) {
        buf[r * NC + c0] = acc0[r] + bb0;
        buf[r * NC + c1] = acc1[r] + bb1;
    }
    __syncthreads();

    const int lane = tid & 63, wvv = tid >> 6;
    for (int rr = 0; rr < 8; ++rr) {
        const int r = wvv * 8 + rr;
        float vals[8];
        float m = -1e30f;
        #pragma unroll
        for (int jx = 0; jx < 8; ++jx) { vals[jx] = buf[r * NC + lane + 64 * jx]; m = fmaxf(m, vals[jx]); }
        #pragma unroll
        for (int off = 32; off; off >>= 1) m = fmaxf(m, __shfl_xor(m, off));
        float s = 0.f;
        #pragma unroll
        for (int jx = 0; jx < 8; ++jx) { vals[jx] = expf(vals[jx] - m); s += vals[jx]; }
        #pragma unroll
        for (int off = 32; off; off >>= 1) s += __shfl_xor(s, off);
        const float inv = 1.f / s;
        #pragma unroll
        for (int jx = 0; jx < 8; ++jx)
            P[(size_t)(t0 + r) * NC + lane + 64 * jx] = vals[jx] * inv;
    }
}

// ---------------- Kernel 3a: colsum[c] = sum_t exp(P[t][c]) ----------------
__global__ __launch_bounds__(256) void colsum_k(const float* __restrict__ P, float* __restrict__ cs)
{
    const int tid = threadIdx.x;
    const int c  = blockIdx.x * 16 + (tid & 15);
    const int tr = tid >> 4;
    float s = 0.f;
    #pragma unroll 8
    for (int t = tr; t < T_STEPS; t += 16) s += expf(P[(size_t)t * NC + c]);
    __shared__ float red[256];
    red[tid] = s; __syncthreads();
    for (int off = 128; off >= 16; off >>= 1) {
        if (tid < off) red[tid] += red[tid + off];
        __syncthreads();
    }
    if (tid < 16) cs[blockIdx.x * 16 + tid] = red[tid];
}

// ---------------- Kernel 3b: out = exp(P) / colsum ----------------
__global__ __launch_bounds__(256) void norm_k(float* P, const float* __restrict__ cs)
{
    size_t i = (size_t)blockIdx.x * 256 + threadIdx.x;
    const size_t n = (size_t)T_STEPS * NC;
    const size_t stride = (size_t)gridDim.x * 256;
    for (; i < n; i += stride) P[i] = expf(P[i]) / cs[i & (NC - 1)];
}

extern "C" void kernel_launch(void* const* d_in, const int* in_sizes, int n_in,
                              void* d_out, int out_size, void* d_ws, size_t ws_size,
                              hipStream_t stream) {
    const float* X    = (const float*)d_in[0];
    const float* h0   = (const float*)d_in[1];
    const float* c0   = (const float*)d_in[2];
    const float* W_ih = (const float*)d_in[3];
    const float* W_hh = (const float*)d_in[4];
    const float* b_ih = (const float*)d_in[5];
    const float* b_hh = (const float*)d_in[6];
    const float* Wd   = (const float*)d_in[7];
    const float* bd   = (const float*)d_in[8];
    float* out = (float*)d_out;

    char* ws = (char*)d_ws;
    ull*   bufp  = (ull*)ws;                     // [2][HID] epoch|h
    float* cs    = (float*)(ws + 16384);         // [NC]
    float* h_all = (float*)(ws + 32768);         // [T, HID]

    init_k<<<1, HID, 0, stream>>>(h0, bufp);
    lstm_rec<<<NWG, TPB, 0, stream>>>(X, c0, W_ih, W_hh, b_ih, b_hh, h_all, bufp);
    dense_softmax<<<T_STEPS / TB, 256, 0, stream>>>(h_all, Wd, bd, out);
    colsum_k<<<NC / 16, 256, 0, stream>>>(out, cs);
    norm_k<<<2048, 256, 0, stream>>>(out, cs);
}